// Round 7
// baseline (2970.373 us; speedup 1.0000x reference)
//
#include <hip/hip_runtime.h>
#include <hip/hip_bf16.h>

typedef __attribute__((ext_vector_type(8))) short bf16x8;
typedef __attribute__((ext_vector_type(4))) float f32x4;

#define MFMA16(a,b,c) __builtin_amdgcn_mfma_f32_16x16x32_bf16(a,b,c,0,0,0)

__device__ inline ushort f2bf(float f){
  union { float f; uint u; } v; v.f = f;
  uint r = v.u + 0x7FFFu + ((v.u >> 16) & 1u);
  return (ushort)(r >> 16);
}
__device__ inline float sigf(float x){ return 1.f/(1.f+__expf(-x)); }
__device__ inline float tanhf_(float x){ return 2.f/(1.f+__expf(-2.f*x)) - 1.f; }

// ---------------- weight fp32 -> bf16 conversion ----------------
__global__ void convert_weights(const float* __restrict__ s0, const float* __restrict__ s1,
                                const float* __restrict__ s2, const float* __restrict__ s3,
                                ushort* __restrict__ dst){
  size_t i4 = ((size_t)blockIdx.x*256 + threadIdx.x)*4;
  int tsel = (int)(i4 >> 21);
  const float* s = (tsel & 2) ? ((tsel & 1) ? s3 : s2) : ((tsel & 1) ? s1 : s0);
  size_t off = i4 & 2097151u;
  float4 v = *(const float4*)&s[off];
  ushort4 o; o.x=f2bf(v.x); o.y=f2bf(v.y); o.z=f2bf(v.z); o.w=f2bf(v.w);
  *(ushort4*)&dst[i4] = o;
}

// ---------------- embed ----------------
__global__ void embed_kernel(const float* __restrict__ obsVel, const float* __restrict__ mean,
                             const float* __restrict__ stdv, const float* __restrict__ encW,
                             const float* __restrict__ encb, ushort* __restrict__ embed){
  int idx = blockIdx.x*256 + threadIdx.x;   // < 32768*64
  int row = idx >> 6, c8 = (idx & 63) * 8;
  float x0 = (obsVel[row*2+0] - mean[0]) / stdv[0];
  float x1 = (obsVel[row*2+1] - mean[1]) / stdv[1];
  ushort o[8];
  #pragma unroll
  for (int j=0;j<8;j++){
    int col = c8 + j;
    o[j] = f2bf(x0*encW[col] + x1*encW[512+col] + encb[col]);
  }
  *(uint4*)&embed[(size_t)row*512 + c8] = *(const uint4*)o;
}

// ---------------- fused LSTM cell step ----------------
// NO LDS, NO barriers. 256 thr = 4 waves stacked in M (wave: 32 rows x 128
// gcols). Block g-tile 128x128. A and B frags stream global->reg (L1/L2
// resident; per-instr pattern = 16 rows x 64B). Register double-buffer
// (named sets), 1-iter prefetch, waves free-run — removes the lockstep
// phase-sum of barrier-coupled LDS staging (rounds 2-6 all ~26us).
#define KSTEPS 16   // K=512 per segment / BK=32

__global__ __launch_bounds__(256, 2) void lstm_cell_kernel(
    const ushort* __restrict__ A0, int lda0,
    const ushort* __restrict__ A1, int lda1,
    const ushort* __restrict__ B0,
    const ushort* __restrict__ B1,
    const float*  __restrict__ bias,
    float* __restrict__ C,
    ushort* __restrict__ H0, int ldh0,
    ushort* __restrict__ H1, int ldh1,
    int nSeg, int czero)
{
  const int tid = threadIdx.x;
  const int w = tid >> 6, lane = tid & 63;
  const int bm = blockIdx.y * 128;
  const int bn = blockIdx.x * 32;            // gate-local col base

  f32x4 acc[2][8];
  #pragma unroll
  for (int m=0;m<2;m++)
    #pragma unroll
    for (int n=0;n<8;n++) acc[m][n] = (f32x4)0.f;

  // per-lane element offsets (k-part: quarter-wave q reads elems [q*8, q*8+8))
  const int kq = (lane >> 4) * 8;
  const int arow0 = bm + w*32 + (lane&15);
  const int arow1 = arow0 + 16;
  // B frag n: gate = n>>1, col = bn + (n&1)*16 + (lane&15); g-row = gate*512+col
  size_t boff[8];
  #pragma unroll
  for (int n=0;n<8;n++){
    int grow = (n>>1)*512 + bn + (n&1)*16 + (lane&15);
    boff[n] = (size_t)grow*512 + kq;
  }

  #define LOADF(AF, BF, Aseg, lda_, Bseg, kt) do { \
    const int k0_ = (kt) << 5; \
    AF[0] = *(const bf16x8*)(Aseg + (size_t)arow0*lda_ + k0_ + kq); \
    AF[1] = *(const bf16x8*)(Aseg + (size_t)arow1*lda_ + k0_ + kq); \
    _Pragma("unroll") \
    for (int n=0;n<8;n++) BF[n] = *(const bf16x8*)(Bseg + boff[n] + k0_); \
  } while(0)

  #define MFMA_ALL(AF, BF) do { \
    __builtin_amdgcn_s_setprio(1); \
    _Pragma("unroll") \
    for (int m=0;m<2;m++) \
      _Pragma("unroll") \
      for (int n=0;n<8;n++) acc[m][n] = MFMA16(AF[m], BF[n], acc[m][n]); \
    __builtin_amdgcn_s_setprio(0); \
  } while(0)

  bf16x8 aA[2], bA[8], aB[2], bB[8];

  for (int seg=0; seg<nSeg; ++seg){
    const ushort* Aseg = seg ? A1 : A0;
    const int lda_     = seg ? lda1 : lda0;
    const ushort* Bseg = seg ? B1 : B0;
    LOADF(aA, bA, Aseg, lda_, Bseg, 0);
    #pragma unroll
    for (int kt=0; kt<KSTEPS-2; kt+=2){
      LOADF(aB, bB, Aseg, lda_, Bseg, kt+1);
      MFMA_ALL(aA, bA);
      LOADF(aA, bA, Aseg, lda_, Bseg, kt+2);
      MFMA_ALL(aB, bB);
    }
    LOADF(aB, bB, Aseg, lda_, Bseg, KSTEPS-1);
    MFMA_ALL(aA, bA);
    MFMA_ALL(aB, bB);
  }
  #undef LOADF
  #undef MFMA_ALL

  // ---- epilogue: bias + gates, c update, h writes ----
  const int r0 = bm + w*32 + ((lane>>4)<<2);
  #pragma unroll
  for (int cc=0;cc<2;cc++){
    const int ccol = bn + cc*16 + (lane&15);
    const float bi = bias[ccol];
    const float bff = bias[512+ccol];
    const float bg = bias[1024+ccol];
    const float bo = bias[1536+ccol];
    #pragma unroll
    for (int m=0;m<2;m++){
      #pragma unroll
      for (int reg=0;reg<4;reg++){
        const int row = r0 + m*16 + reg;
        float gi = acc[m][0+cc][reg] + bi;
        float gf = acc[m][2+cc][reg] + bff;
        float gg = acc[m][4+cc][reg] + bg;
        float go = acc[m][6+cc][reg] + bo;
        size_t cidx = (size_t)row*512 + ccol;
        float cv = czero ? 0.f : C[cidx];
        float cn = sigf(gf)*cv + sigf(gi)*tanhf_(gg);
        float hv = sigf(go)*tanhf_(cn);
        C[cidx] = cn;
        ushort hb = f2bf(hv);
        H0[(size_t)row*ldh0 + ccol] = hb;
        if (H1) H1[(size_t)row*ldh1 + ccol] = hb;
      }
    }
  }
}

// ---------------- projection + cumsum ----------------
__global__ void final_kernel(const ushort* __restrict__ pred, const float* __restrict__ decW,
                             const float* __restrict__ decb, const float* __restrict__ mean,
                             const float* __restrict__ stdv, const float* __restrict__ obs,
                             float* __restrict__ out){
  int w = threadIdx.x >> 6, lane = threadIdx.x & 63;
  int b = blockIdx.x*4 + w;
  float w0[8], w1[8];
  #pragma unroll
  for (int j=0;j<8;j++){
    int k = lane*8 + j;
    w0[j] = decW[k*2+0];
    w1[j] = decW[k*2+1];
  }
  float cum0 = 0.f, cum1 = 0.f;
  float m0 = mean[0], m1 = mean[1], sv0 = stdv[0], sv1 = stdv[1];
  float o0 = obs[(b*8+7)*2+0], o1 = obs[(b*8+7)*2+1];
  float db0 = decb[0], db1 = decb[1];
  for (int t=0;t<12;t++){
    const uint4 q = *(const uint4*)&pred[((size_t)b*12+t)*512 + lane*8];
    uint u[4] = {q.x,q.y,q.z,q.w};
    float s0=0.f, s1=0.f;
    #pragma unroll
    for (int p=0;p<4;p++){
      float lo = __uint_as_float(u[p]<<16);
      float hi = __uint_as_float(u[p]&0xffff0000u);
      s0 += lo*w0[2*p] + hi*w0[2*p+1];
      s1 += lo*w1[2*p] + hi*w1[2*p+1];
    }
    #pragma unroll
    for (int off=32; off>0; off>>=1){ s0 += __shfl_down(s0, off); s1 += __shfl_down(s1, off); }
    if (lane==0){
      cum0 += (s0+db0)*sv0 + m0;
      cum1 += (s1+db1)*sv1 + m1;
      out[((size_t)b*12+t)*2+0] = cum0 + o0;
      out[((size_t)b*12+t)*2+1] = cum1 + o1;
    }
  }
}

extern "C" void kernel_launch(void* const* d_in, const int* in_sizes, int n_in,
                              void* d_out, int out_size, void* d_ws, size_t ws_size,
                              hipStream_t stream) {
  const float* obs      = (const float*)d_in[0];
  const float* obsVel   = (const float*)d_in[1];
  const float* mean     = (const float*)d_in[2];
  const float* stdv     = (const float*)d_in[3];
  const float* encW     = (const float*)d_in[5];
  const float* encb     = (const float*)d_in[6];
  const float* decW     = (const float*)d_in[7];
  const float* decb     = (const float*)d_in[8];
  const float* lstm_Wih = (const float*)d_in[9];
  const float* lstm_Whh = (const float*)d_in[10];
  const float* lstm_b   = (const float*)d_in[11];
  const float* cell_Wih = (const float*)d_in[12];
  const float* cell_Whh = (const float*)d_in[13];
  const float* cell_b   = (const float*)d_in[14];

  char* ws = (char*)d_ws;
  ushort* wbf   = (ushort*)ws;                       // 16 MB
  ushort* embed = (ushort*)(ws + (16ull<<20));       // 32 MB
  ushort* h0[2] = {(ushort*)(ws + (48ull<<20)), (ushort*)(ws + (52ull<<20))};
  ushort* h1[2] = {(ushort*)(ws + (56ull<<20)), (ushort*)(ws + (60ull<<20))};
  float*  c0    = (float*)(ws + (64ull<<20));
  float*  c1    = (float*)(ws + (72ull<<20));
  ushort* pred  = (ushort*)(ws + (80ull<<20));       // 48 MB

  ushort* w_lstm_ih = wbf;
  ushort* w_lstm_hh = wbf + 2097152;
  ushort* w_cell_ih = wbf + 4194304;
  ushort* w_cell_hh = wbf + 6291456;

  convert_weights<<<8192, 256, 0, stream>>>(lstm_Wih, lstm_Whh, cell_Wih, cell_Whh, wbf);
  embed_kernel<<<8192, 256, 0, stream>>>(obsVel, mean, stdv, encW, encb, embed);

  dim3 grid(16, 32);
  int cur0 = 0, cur1 = 0;
  for (int t=0;t<8;t++){
    int ns = (t==0) ? 1 : 2;
    int cz = (t==0) ? 1 : 0;
    lstm_cell_kernel<<<grid, 256, 0, stream>>>(embed + t*512, 4096, h0[cur0], 512,
        w_lstm_ih, w_lstm_hh, lstm_b, c0, h0[cur0^1], 512, (ushort*)nullptr, 0, ns, cz);
    lstm_cell_kernel<<<grid, 256, 0, stream>>>(h0[cur0^1], 512, h1[cur1], 512,
        w_lstm_ih + 1048576, w_lstm_hh + 1048576, lstm_b + 2048, c1, h1[cur1^1], 512,
        (t==7) ? pred : (ushort*)nullptr, 6144, ns, cz);
    cur0 ^= 1; cur1 ^= 1;
  }
  for (int s=1;s<12;s++){
    lstm_cell_kernel<<<grid, 256, 0, stream>>>(pred + (s-1)*512, 6144, h0[cur0], 512,
        w_cell_ih, w_cell_hh, cell_b, c0, h0[cur0^1], 512, (ushort*)nullptr, 0, 2, 0);
    lstm_cell_kernel<<<grid, 256, 0, stream>>>(h0[cur0^1], 512, h1[cur1], 512,
        w_cell_ih + 1048576, w_cell_hh + 1048576, cell_b + 2048, c1, h1[cur1^1], 512,
        pred + s*512, 6144, 2, 0);
    cur0 ^= 1; cur1 ^= 1;
  }
  final_kernel<<<1024, 256, 0, stream>>>(pred, decW, decb, mean, stdv, obs, (float*)d_out);
}

// Round 8
// 1213.013 us; speedup vs baseline: 2.4488x; 2.4488x over previous
//
#include <hip/hip_runtime.h>
#include <hip/hip_bf16.h>

typedef __attribute__((ext_vector_type(8))) short bf16x8;
typedef __attribute__((ext_vector_type(16))) float f32x16;

#define MFMA32(a,b,c) __builtin_amdgcn_mfma_f32_32x32x16_bf16(a,b,c,0,0,0)

__device__ inline ushort f2bf(float f){
  union { float f; uint u; } v; v.f = f;
  uint r = v.u + 0x7FFFu + ((v.u >> 16) & 1u);
  return (ushort)(r >> 16);
}
__device__ inline float sigf(float x){ return 1.f/(1.f+__expf(-x)); }
__device__ inline float tanhf_(float x){ return 2.f/(1.f+__expf(-2.f*x)) - 1.f; }

__device__ inline void gload_lds16(const ushort* g, ushort* lds){
  __builtin_amdgcn_global_load_lds(
      (const __attribute__((address_space(1))) void*)g,
      (__attribute__((address_space(3))) void*)lds, 16, 0, 0);
}

// ---------------- weight fp32 -> bf16 conversion ----------------
__global__ void convert_weights(const float* __restrict__ s0, const float* __restrict__ s1,
                                const float* __restrict__ s2, const float* __restrict__ s3,
                                ushort* __restrict__ dst){
  size_t i4 = ((size_t)blockIdx.x*256 + threadIdx.x)*4;
  int tsel = (int)(i4 >> 21);
  const float* s = (tsel & 2) ? ((tsel & 1) ? s3 : s2) : ((tsel & 1) ? s1 : s0);
  size_t off = i4 & 2097151u;
  float4 v = *(const float4*)&s[off];
  ushort4 o; o.x=f2bf(v.x); o.y=f2bf(v.y); o.z=f2bf(v.z); o.w=f2bf(v.w);
  *(ushort4*)&dst[i4] = o;
}

// ---------------- embed ----------------
__global__ void embed_kernel(const float* __restrict__ obsVel, const float* __restrict__ mean,
                             const float* __restrict__ stdv, const float* __restrict__ encW,
                             const float* __restrict__ encb, ushort* __restrict__ embed){
  int idx = blockIdx.x*256 + threadIdx.x;   // < 32768*64
  int row = idx >> 6, c8 = (idx & 63) * 8;
  float x0 = (obsVel[row*2+0] - mean[0]) / stdv[0];
  float x1 = (obsVel[row*2+1] - mean[1]) / stdv[1];
  ushort o[8];
  #pragma unroll
  for (int j=0;j<8;j++){
    int col = c8 + j;
    o[j] = f2bf(x0*encW[col] + x1*encW[512+col] + encb[col]);
  }
  *(uint4*)&embed[(size_t)row*512 + c8] = *(const uint4*)o;
}

// ---------------- fused LSTM cell step (32x32x16 MFMA) ----------------
// 256 thr = 4 waves M-stacked (wave: 32 rows x 128 gcols = 4 gates x 32).
// Block tile 128x128 of g. BK=32. Per wave-iter: 10 ds_read_b128 -> 8 MFMA
// (32x32x16), vs 18->16 with 16x16x32 (1.8x less LDS read traffic/FLOP).
// LDS: row-pair packing, 64 LDS-rows x 128B per tile; logical row r (64B) at
// LDS row r&63, slot(r,c) = ((r>>6)*4 + c) ^ (r&7). Frag reads: consecutive
// 8-lane groups span r&7=0..7 -> 8 distinct 16B slots -> conflict-free.
// Staging: linear LDS dest (global_load_lds), inverse-swizzled global src.
// 2 bufs x 16 KB = 32 KB -> 2 blocks/CU. One __syncthreads per iter.
#define NKT_SEG 16   // K=512 per segment / BK=32

__global__ __launch_bounds__(256, 2) void lstm_cell_kernel(
    const ushort* __restrict__ A0, int lda0,
    const ushort* __restrict__ A1, int lda1,
    const ushort* __restrict__ B0,
    const ushort* __restrict__ B1,
    const float*  __restrict__ bias,
    float* __restrict__ C,
    ushort* __restrict__ H0, int ldh0,
    ushort* __restrict__ H1, int ldh1,
    int nSeg, int czero)
{
  __shared__ ushort aL[2][4096];   // 64 LDS-rows x 64 ushort (128 B)
  __shared__ ushort bL[2][4096];
  const int tid = threadIdx.x;
  const int w = tid >> 6, lane = tid & 63;
  const int bm = blockIdx.y * 128;
  const int bn = blockIdx.x * 32;            // gate-local col base

  f32x16 acc[4];
  #pragma unroll
  for (int g=0;g<4;g++) acc[g] = (f32x16)0.f;

  // ---- staging addresses: 2 chunks/thread/tile (A) + 2 (B); inverse swizzle ----
  // chunk i -> LDS byte i*16; ldsRow=i>>3, slot=i&7; A4=slot^(ldsRow&7);
  // tr = (A4>>2)*64 + ldsRow, c = A4&3.
  int atr[2];           // A logical row (block-local)
  size_t boff[2];       // B element offset within segment (add k0)
  int cS[2], ldsO[2];
  #pragma unroll
  for (int p=0;p<2;p++){
    int i = p*256 + tid;
    int ldsRow = i>>3, slot = i&7;
    int A4 = slot ^ (ldsRow&7);
    int tr = ((A4>>2)<<6) + ldsRow;
    int c  = A4 & 3;
    atr[p]  = tr;
    boff[p] = (size_t)((tr>>5)*512 + bn + (tr&31))*512 + c*8;
    cS[p]   = c*8;
    ldsO[p] = (p*256 + (tid & ~63)) * 8;   // ushort idx, wave-uniform base
  }

  // ---- frag read offsets (ushort units) ----
  int aOff[2], bOff[4][2];
  #pragma unroll
  for (int ks=0;ks<2;ks++){
    int tr = w*32 + (lane&31);
    int slot = (((tr>>6)<<2) + ks*2 + (lane>>5)) ^ (tr&7);
    aOff[ks] = (tr&63)*64 + slot*8;
  }
  #pragma unroll
  for (int g=0;g<4;g++)
    #pragma unroll
    for (int ks=0;ks<2;ks++){
      int tr = g*32 + (lane&31);
      int slot = (((tr>>6)<<2) + ks*2 + (lane>>5)) ^ (tr&7);
      bOff[g][ks] = (tr&63)*64 + slot*8;
    }

  #define STAGE(bi, kt) do { \
    const ushort* Aseg = ((kt) < NKT_SEG) ? A0 : A1; \
    const int lda_     = ((kt) < NKT_SEG) ? lda0 : lda1; \
    const ushort* Bseg = ((kt) < NKT_SEG) ? B0 : B1; \
    const int k0_ = ((kt) & (NKT_SEG-1)) << 5; \
    _Pragma("unroll") \
    for (int p=0;p<2;p++){ \
      gload_lds16(Aseg + (size_t)(bm + atr[p])*lda_ + k0_ + cS[p], &aL[bi][ldsO[p]]); \
      gload_lds16(Bseg + boff[p] + k0_, &bL[bi][ldsO[p]]); \
    } \
  } while(0)

  const int nkt = nSeg * NKT_SEG;

  STAGE(0, 0);
  __syncthreads();

  for (int kt=0; kt<nkt; ++kt){
    const int cur = kt & 1;
    if (kt+1 < nkt) STAGE(cur^1, kt+1);
    bf16x8 af0, af1, bf[4][2];
    af0 = *(const bf16x8*)&aL[cur][aOff[0]];
    af1 = *(const bf16x8*)&aL[cur][aOff[1]];
    #pragma unroll
    for (int g=0;g<4;g++){
      bf[g][0] = *(const bf16x8*)&bL[cur][bOff[g][0]];
      bf[g][1] = *(const bf16x8*)&bL[cur][bOff[g][1]];
    }
    __builtin_amdgcn_s_setprio(1);
    #pragma unroll
    for (int g=0;g<4;g++) acc[g] = MFMA32(af0, bf[g][0], acc[g]);
    #pragma unroll
    for (int g=0;g<4;g++) acc[g] = MFMA32(af1, bf[g][1], acc[g]);
    __builtin_amdgcn_s_setprio(0);
    __syncthreads();
  }
  #undef STAGE

  // ---- epilogue: bias + gates, c update, h writes ----
  // C/D layout (m74/m101): col = lane&31, row = (reg&3) + 8*(reg>>2) + 4*(lane>>5)
  const int colc = bn + (lane&31);
  const float b_i = bias[colc];
  const float b_f = bias[512+colc];
  const float b_g = bias[1024+colc];
  const float b_o = bias[1536+colc];
  #pragma unroll
  for (int reg=0;reg<16;reg++){
    const int rl = (reg&3) + ((reg>>2)<<3) + ((lane>>5)<<2);
    const int row = bm + w*32 + rl;
    float gi = acc[0][reg] + b_i;
    float gf = acc[1][reg] + b_f;
    float gg = acc[2][reg] + b_g;
    float go = acc[3][reg] + b_o;
    size_t cidx = (size_t)row*512 + colc;
    float cv = czero ? 0.f : C[cidx];
    float cn = sigf(gf)*cv + sigf(gi)*tanhf_(gg);
    float hv = sigf(go)*tanhf_(cn);
    C[cidx] = cn;
    ushort hb = f2bf(hv);
    H0[(size_t)row*ldh0 + colc] = hb;
    if (H1) H1[(size_t)row*ldh1 + colc] = hb;
  }
}

// ---------------- projection + cumsum ----------------
__global__ void final_kernel(const ushort* __restrict__ pred, const float* __restrict__ decW,
                             const float* __restrict__ decb, const float* __restrict__ mean,
                             const float* __restrict__ stdv, const float* __restrict__ obs,
                             float* __restrict__ out){
  int w = threadIdx.x >> 6, lane = threadIdx.x & 63;
  int b = blockIdx.x*4 + w;
  float w0[8], w1[8];
  #pragma unroll
  for (int j=0;j<8;j++){
    int k = lane*8 + j;
    w0[j] = decW[k*2+0];
    w1[j] = decW[k*2+1];
  }
  float cum0 = 0.f, cum1 = 0.f;
  float m0 = mean[0], m1 = mean[1], sv0 = stdv[0], sv1 = stdv[1];
  float o0 = obs[(b*8+7)*2+0], o1 = obs[(b*8+7)*2+1];
  float db0 = decb[0], db1 = decb[1];
  for (int t=0;t<12;t++){
    const uint4 q = *(const uint4*)&pred[((size_t)b*12+t)*512 + lane*8];
    uint u[4] = {q.x,q.y,q.z,q.w};
    float s0=0.f, s1=0.f;
    #pragma unroll
    for (int p=0;p<4;p++){
      float lo = __uint_as_float(u[p]<<16);
      float hi = __uint_as_float(u[p]&0xffff0000u);
      s0 += lo*w0[2*p] + hi*w0[2*p+1];
      s1 += lo*w1[2*p] + hi*w1[2*p+1];
    }
    #pragma unroll
    for (int off=32; off>0; off>>=1){ s0 += __shfl_down(s0, off); s1 += __shfl_down(s1, off); }
    if (lane==0){
      cum0 += (s0+db0)*sv0 + m0;
      cum1 += (s1+db1)*sv1 + m1;
      out[((size_t)b*12+t)*2+0] = cum0 + o0;
      out[((size_t)b*12+t)*2+1] = cum1 + o1;
    }
  }
}

extern "C" void kernel_launch(void* const* d_in, const int* in_sizes, int n_in,
                              void* d_out, int out_size, void* d_ws, size_t ws_size,
                              hipStream_t stream) {
  const float* obs      = (const float*)d_in[0];
  const float* obsVel   = (const float*)d_in[1];
  const float* mean     = (const float*)d_in[2];
  const float* stdv     = (const float*)d_in[3];
  const float* encW     = (const float*)d_in[5];
  const float* encb     = (const float*)d_in[6];
  const float* decW     = (const float*)d_in[7];
  const float* decb     = (const float*)d_in[8];
  const float* lstm_Wih = (const float*)d_in[9];
  const float* lstm_Whh = (const float*)d_in[10];
  const float* lstm_b   = (const float*)d_in[11];
  const float* cell_Wih = (const float*)d_in[12];
  const float* cell_Whh = (const float*)d_in[13];
  const float* cell_b   = (const float*)d_in[14];

  char* ws = (char*)d_ws;
  ushort* wbf   = (ushort*)ws;                       // 16 MB
  ushort* embed = (ushort*)(ws + (16ull<<20));       // 32 MB
  ushort* h0[2] = {(ushort*)(ws + (48ull<<20)), (ushort*)(ws + (52ull<<20))};
  ushort* h1[2] = {(ushort*)(ws + (56ull<<20)), (ushort*)(ws + (60ull<<20))};
  float*  c0    = (float*)(ws + (64ull<<20));
  float*  c1    = (float*)(ws + (72ull<<20));
  ushort* pred  = (ushort*)(ws + (80ull<<20));       // 48 MB

  ushort* w_lstm_ih = wbf;
  ushort* w_lstm_hh = wbf + 2097152;
  ushort* w_cell_ih = wbf + 4194304;
  ushort* w_cell_hh = wbf + 6291456;

  convert_weights<<<8192, 256, 0, stream>>>(lstm_Wih, lstm_Whh, cell_Wih, cell_Whh, wbf);
  embed_kernel<<<8192, 256, 0, stream>>>(obsVel, mean, stdv, encW, encb, embed);

  dim3 grid(16, 32);
  int cur0 = 0, cur1 = 0;
  for (int t=0;t<8;t++){
    int ns = (t==0) ? 1 : 2;
    int cz = (t==0) ? 1 : 0;
    lstm_cell_kernel<<<grid, 256, 0, stream>>>(embed + t*512, 4096, h0[cur0], 512,
        w_lstm_ih, w_lstm_hh, lstm_b, c0, h0[cur0^1], 512, (ushort*)nullptr, 0, ns, cz);
    lstm_cell_kernel<<<grid, 256, 0, stream>>>(h0[cur0^1], 512, h1[cur1], 512,
        w_lstm_ih + 1048576, w_lstm_hh + 1048576, lstm_b + 2048, c1, h1[cur1^1], 512,
        (t==7) ? pred : (ushort*)nullptr, 6144, ns, cz);
    cur0 ^= 1; cur1 ^= 1;
  }
  for (int s=1;s<12;s++){
    lstm_cell_kernel<<<grid, 256, 0, stream>>>(pred + (s-1)*512, 6144, h0[cur0], 512,
        w_cell_ih, w_cell_hh, cell_b, c0, h0[cur0^1], 512, (ushort*)nullptr, 0, 2, 0);
    lstm_cell_kernel<<<grid, 256, 0, stream>>>(h0[cur0^1], 512, h1[cur1], 512,
        w_cell_ih + 1048576, w_cell_hh + 1048576, cell_b + 2048, c1, h1[cur1^1], 512,
        pred + s*512, 6144, 2, 0);
    cur0 ^= 1; cur1 ^= 1;
  }
  final_kernel<<<1024, 256, 0, stream>>>(pred, decW, decb, mean, stdv, obs, (float*)d_out);
}